// Round 1
// baseline (5327.182 us; speedup 1.0000x reference)
//
#include <hip/hip_runtime.h>
#include <hip/hip_bf16.h>
#include <math.h>

typedef __bf16 bf16x8 __attribute__((ext_vector_type(8)));
typedef __bf16 bf16x4 __attribute__((ext_vector_type(4)));
typedef float  f32x4  __attribute__((ext_vector_type(4)));

constexpr int kS   = 2048;
constexpr int kH   = 4096;
constexpr int kNH  = 32;
constexpr int kNKV = 8;
constexpr int kHD  = 128;
constexpr int kKVD = kNKV * kHD;   // 1024

// ---------------------------------------------------------------- cast f32->bf16
__global__ void cast_bf16(const float* __restrict__ in, __bf16* __restrict__ out, int n4) {
    int i = blockIdx.x * blockDim.x + threadIdx.x;
    if (i < n4) {
        float4 f = ((const float4*)in)[i];
        bf16x4 o;
        o[0] = (__bf16)f.x; o[1] = (__bf16)f.y; o[2] = (__bf16)f.z; o[3] = (__bf16)f.w;
        ((bf16x4*)out)[i] = o;
    }
}

// ---------------------------------------------------------------- NT GEMM, bf16 in / f32 out
// C[M,N] = A[M,K] * B[N,K]^T ; A,B row-major K-contiguous. M%128==0, N%128==0, K%32==0.
constexpr int BM = 128, BN = 128, BK = 32, KP = 40;  // KP: pad 32->40 elems (80B, 16B-aligned)

__global__ __launch_bounds__(256) void gemm_nt(const __bf16* __restrict__ A,
                                               const __bf16* __restrict__ B,
                                               float* __restrict__ C,
                                               int M, int N, int K) {
    __shared__ __align__(16) __bf16 As[BM * KP];
    __shared__ __align__(16) __bf16 Bs[BN * KP];
    const int tid  = threadIdx.x;
    const int m0   = blockIdx.y * BM, n0 = blockIdx.x * BN;
    const int wave = tid >> 6, lane = tid & 63;
    const int wm   = (wave >> 1) * 64, wn = (wave & 1) * 64;
    const int lr   = lane & 15;            // m (or n) within 16-tile
    const int lk   = (lane >> 4) * 8;      // k offset of this lane's 8 elems
    const int sr   = tid >> 2;             // staging row 0..63
    const int sc   = (tid & 3) * 8;        // staging k-chunk

    f32x4 acc[4][4];
#pragma unroll
    for (int i = 0; i < 4; i++)
#pragma unroll
        for (int j = 0; j < 4; j++) acc[i][j] = (f32x4)(0.f);

    const __bf16* Ar0 = A + (size_t)(m0 + sr) * K + sc;
    const __bf16* Ar1 = A + (size_t)(m0 + sr + 64) * K + sc;
    const __bf16* Br0 = B + (size_t)(n0 + sr) * K + sc;
    const __bf16* Br1 = B + (size_t)(n0 + sr + 64) * K + sc;

    for (int k0 = 0; k0 < K; k0 += BK) {
        *(bf16x8*)&As[sr * KP + sc]        = *(const bf16x8*)(Ar0 + k0);
        *(bf16x8*)&As[(sr + 64) * KP + sc] = *(const bf16x8*)(Ar1 + k0);
        *(bf16x8*)&Bs[sr * KP + sc]        = *(const bf16x8*)(Br0 + k0);
        *(bf16x8*)&Bs[(sr + 64) * KP + sc] = *(const bf16x8*)(Br1 + k0);
        __syncthreads();

        bf16x8 af[4], bfr[4];
#pragma unroll
        for (int i = 0; i < 4; i++) af[i]  = *(const bf16x8*)&As[(wm + i * 16 + lr) * KP + lk];
#pragma unroll
        for (int j = 0; j < 4; j++) bfr[j] = *(const bf16x8*)&Bs[(wn + j * 16 + lr) * KP + lk];

#pragma unroll
        for (int i = 0; i < 4; i++)
#pragma unroll
            for (int j = 0; j < 4; j++)
                acc[i][j] = __builtin_amdgcn_mfma_f32_16x16x32_bf16(af[i], bfr[j], acc[i][j], 0, 0, 0);
        __syncthreads();
    }

    // C/D layout (HW-verified): col = lane&15, row = (lane>>4)*4 + reg
    const int cr = (lane >> 4) * 4, cc = lane & 15;
#pragma unroll
    for (int i = 0; i < 4; i++)
#pragma unroll
        for (int j = 0; j < 4; j++) {
            float* Cp = C + (size_t)(m0 + wm + i * 16 + cr) * N + (n0 + wn + j * 16 + cc);
#pragma unroll
            for (int r = 0; r < 4; r++) Cp[(size_t)r * N] = acc[i][j][r];
        }
}

// ---------------------------------------------------------------- RoPE in-place on q [S,4096] and k [S,1024]
__global__ void rope_kernel(float* __restrict__ q, float* __restrict__ k) {
    int idx  = blockIdx.x * 256 + threadIdx.x;     // S * 40 heads * 64 pairs
    int d    = idx & 63;
    int rest = idx >> 6;
    int h    = rest % (kNH + kNKV);
    int s    = rest / (kNH + kNKV);
    float inv_freq = powf(500000.0f, -(float)d * (1.0f / 64.0f));
    float ang = (float)s * inv_freq;
    float sn, cs;
    sincosf(ang, &sn, &cs);
    float* base = (h < kNH) ? (q + (size_t)s * kH + h * kHD)
                            : (k + (size_t)s * kKVD + (h - kNH) * kHD);
    float a = base[d], b = base[d + 64];
    base[d]      = a * cs - b * sn;
    base[d + 64] = b * cs + a * sn;
}

// ---------------------------------------------------------------- causal GQA attention, online softmax
// one wave per (head, query row); 4 consecutive rows of same head per block (KV L1 reuse)
__global__ __launch_bounds__(256) void attn_kernel(const float* __restrict__ q,
                                                   const float* __restrict__ k,
                                                   const float* __restrict__ v,
                                                   __bf16* __restrict__ o) {
    const int wave = threadIdx.x >> 6, lane = threadIdx.x & 63;
    const int blk  = blockIdx.x;
    const int h    = blk >> 9;                     // 512 blocks per head (S/4)
    const int si   = ((blk & 511) << 2) | wave;
    const int hk   = h >> 2;                       // GQA: kv head = h / 4
    const float* qp = q + (size_t)si * kH + h * kHD;
    const float* kb = k + hk * kHD;
    const float* vb = v + hk * kHD;
    const int d0 = lane * 2;
    const float q0 = qp[d0], q1 = qp[d0 + 1];
    float m = -3.4e38f, l = 0.f, a0 = 0.f, a1 = 0.f;
    const float scale = 0.088388347648318447f;     // 1/sqrt(128)
    for (int j = 0; j <= si; ++j) {
        const float* kr = kb + (size_t)j * kKVD;
        float p = q0 * kr[d0] + q1 * kr[d0 + 1];
        p += __shfl_xor(p, 32);
        p += __shfl_xor(p, 16);
        p += __shfl_xor(p, 8);
        p += __shfl_xor(p, 4);
        p += __shfl_xor(p, 2);
        p += __shfl_xor(p, 1);
        float s  = p * scale;
        float mn = fmaxf(m, s);
        float alpha = __expf(m - mn);
        float pj    = __expf(s - mn);
        const float* vr = vb + (size_t)j * kKVD;
        l  = l * alpha + pj;
        a0 = a0 * alpha + pj * vr[d0];
        a1 = a1 * alpha + pj * vr[d0 + 1];
        m = mn;
    }
    float inv = 1.f / l;
    __bf16* op = o + (size_t)si * kH + h * kHD;
    op[d0]     = (__bf16)(a0 * inv);
    op[d0 + 1] = (__bf16)(a1 * inv);
}

// ---------------------------------------------------------------- launch
extern "C" void kernel_launch(void* const* d_in, const int* in_sizes, int n_in,
                              void* d_out, int out_size, void* d_ws, size_t ws_size,
                              hipStream_t stream) {
    const float* x  = (const float*)d_in[0];
    const float* wq = (const float*)d_in[1];
    const float* wk = (const float*)d_in[2];
    const float* wv = (const float*)d_in[3];
    const float* wo = (const float*)d_in[4];
    float* out = (float*)d_out;

    char* p = (char*)d_ws;
    auto alloc = [&](size_t bytes) {
        char* r = p;
        p += (bytes + 255) & ~(size_t)255;
        return r;
    };
    // overlaid buffers; reuse is safe because all launches are stream-ordered
    __bf16* xb  = (__bf16*)alloc((size_t)kS * kH * 2);      // x bf16; later reused for attn out
    __bf16* wb1 = (__bf16*)alloc((size_t)kH * kH * 2);      // wq, later wo
    __bf16* wb2 = (__bf16*)alloc((size_t)kKVD * kH * 2);    // wk, later wv
    float*  qf  = (float*)alloc((size_t)kS * kH * 4);
    float*  kf  = (float*)alloc((size_t)kS * kKVD * 4);
    float*  vf  = (float*)alloc((size_t)kS * kKVD * 4);
    __bf16* ao  = xb;                                        // attention output overlays xb

    auto cvt = [&](const float* in, __bf16* o, size_t n) {
        int n4 = (int)(n / 4);
        cast_bf16<<<dim3((n4 + 255) / 256), dim3(256), 0, stream>>>(in, o, n4);
    };

    cvt(x, xb, (size_t)kS * kH);
    cvt(wq, wb1, (size_t)kH * kH);
    gemm_nt<<<dim3(kH / BN, kS / BM), 256, 0, stream>>>(xb, wb1, qf, kS, kH, kH);

    cvt(wk, wb2, (size_t)kKVD * kH);
    gemm_nt<<<dim3(kKVD / BN, kS / BM), 256, 0, stream>>>(xb, wb2, kf, kS, kKVD, kH);
    cvt(wv, wb2, (size_t)kKVD * kH);
    gemm_nt<<<dim3(kKVD / BN, kS / BM), 256, 0, stream>>>(xb, wb2, vf, kS, kKVD, kH);

    rope_kernel<<<dim3(kS * (kNH + kNKV) * 64 / 256), 256, 0, stream>>>(qf, kf);

    attn_kernel<<<dim3(kNH * kS / 4), 256, 0, stream>>>(qf, kf, vf, ao);

    cvt(wo, wb1, (size_t)kH * kH);
    gemm_nt<<<dim3(kH / BN, kS / BM), 256, 0, stream>>>(ao, wb1, out, kS, kH, kH);
}

// Round 2
// 746.358 us; speedup vs baseline: 7.1376x; 7.1376x over previous
//
#include <hip/hip_runtime.h>
#include <hip/hip_bf16.h>
#include <math.h>

typedef __bf16 bf16x8 __attribute__((ext_vector_type(8)));
typedef __bf16 bf16x4 __attribute__((ext_vector_type(4)));
typedef unsigned short u16x8 __attribute__((ext_vector_type(8)));
typedef float  f32x4  __attribute__((ext_vector_type(4)));

constexpr int kS   = 2048;
constexpr int kH   = 4096;
constexpr int kNH  = 32;
constexpr int kNKV = 8;
constexpr int kHD  = 128;
constexpr int kKVD = kNKV * kHD;   // 1024

// ---------------------------------------------------------------- cast f32->bf16
__global__ void cast_bf16(const float* __restrict__ in, __bf16* __restrict__ out, int n4) {
    int i = blockIdx.x * blockDim.x + threadIdx.x;
    if (i < n4) {
        float4 f = ((const float4*)in)[i];
        bf16x4 o;
        o[0] = (__bf16)f.x; o[1] = (__bf16)f.y; o[2] = (__bf16)f.z; o[3] = (__bf16)f.w;
        ((bf16x4*)out)[i] = o;
    }
}

// ---------------------------------------------------------------- NT GEMM, bf16 in / f32 out
constexpr int BM = 128, BN = 128, BK = 32, KP = 40;

__global__ __launch_bounds__(256) void gemm_nt(const __bf16* __restrict__ A,
                                               const __bf16* __restrict__ B,
                                               float* __restrict__ C,
                                               int M, int N, int K) {
    __shared__ __align__(16) __bf16 As[BM * KP];
    __shared__ __align__(16) __bf16 Bs[BN * KP];
    const int tid  = threadIdx.x;
    const int m0   = blockIdx.y * BM, n0 = blockIdx.x * BN;
    const int wave = tid >> 6, lane = tid & 63;
    const int wm   = (wave >> 1) * 64, wn = (wave & 1) * 64;
    const int lr   = lane & 15;
    const int lk   = (lane >> 4) * 8;
    const int sr   = tid >> 2;
    const int sc   = (tid & 3) * 8;

    f32x4 acc[4][4];
#pragma unroll
    for (int i = 0; i < 4; i++)
#pragma unroll
        for (int j = 0; j < 4; j++) acc[i][j] = (f32x4)(0.f);

    const __bf16* Ar0 = A + (size_t)(m0 + sr) * K + sc;
    const __bf16* Ar1 = A + (size_t)(m0 + sr + 64) * K + sc;
    const __bf16* Br0 = B + (size_t)(n0 + sr) * K + sc;
    const __bf16* Br1 = B + (size_t)(n0 + sr + 64) * K + sc;

    for (int k0 = 0; k0 < K; k0 += BK) {
        *(bf16x8*)&As[sr * KP + sc]        = *(const bf16x8*)(Ar0 + k0);
        *(bf16x8*)&As[(sr + 64) * KP + sc] = *(const bf16x8*)(Ar1 + k0);
        *(bf16x8*)&Bs[sr * KP + sc]        = *(const bf16x8*)(Br0 + k0);
        *(bf16x8*)&Bs[(sr + 64) * KP + sc] = *(const bf16x8*)(Br1 + k0);
        __syncthreads();

        bf16x8 af[4], bfr[4];
#pragma unroll
        for (int i = 0; i < 4; i++) af[i]  = *(const bf16x8*)&As[(wm + i * 16 + lr) * KP + lk];
#pragma unroll
        for (int j = 0; j < 4; j++) bfr[j] = *(const bf16x8*)&Bs[(wn + j * 16 + lr) * KP + lk];

#pragma unroll
        for (int i = 0; i < 4; i++)
#pragma unroll
            for (int j = 0; j < 4; j++)
                acc[i][j] = __builtin_amdgcn_mfma_f32_16x16x32_bf16(af[i], bfr[j], acc[i][j], 0, 0, 0);
        __syncthreads();
    }

    const int cr = (lane >> 4) * 4, cc = lane & 15;
#pragma unroll
    for (int i = 0; i < 4; i++)
#pragma unroll
        for (int j = 0; j < 4; j++) {
            float* Cp = C + (size_t)(m0 + wm + i * 16 + cr) * N + (n0 + wn + j * 16 + cc);
#pragma unroll
            for (int r = 0; r < 4; r++) Cp[(size_t)r * N] = acc[i][j][r];
        }
}

// ---------------------------------------------------------------- RoPE + scale + cast to bf16
// qf [S,4096] -> qb (scaled by 1/sqrt(128)) ; kf [S,1024] -> kb
__global__ void rope_cast(const float* __restrict__ qf, const float* __restrict__ kf,
                          __bf16* __restrict__ qb, __bf16* __restrict__ kb) {
    int idx  = blockIdx.x * 256 + threadIdx.x;     // S * 40 * 64
    int d    = idx & 63;
    int rest = idx >> 6;
    int hh   = rest % (kNH + kNKV);
    int s    = rest / (kNH + kNKV);
    float inv_freq = powf(500000.0f, -(float)d * (1.0f / 64.0f));
    float ang = (float)s * inv_freq;
    float sn, cs;
    sincosf(ang, &sn, &cs);
    if (hh < kNH) {
        const float* src = qf + (size_t)s * kH + hh * kHD;
        __bf16* dst = qb + (size_t)s * kH + hh * kHD;
        const float sc = 0.088388347648318447f;    // 1/sqrt(128)
        float a = src[d], b = src[d + 64];
        dst[d]      = (__bf16)((a * cs - b * sn) * sc);
        dst[d + 64] = (__bf16)((b * cs + a * sn) * sc);
    } else {
        int h2 = hh - kNH;
        const float* src = kf + (size_t)s * kKVD + h2 * kHD;
        __bf16* dst = kb + (size_t)s * kKVD + h2 * kHD;
        float a = src[d], b = src[d + 64];
        dst[d]      = (__bf16)(a * cs - b * sn);
        dst[d + 64] = (__bf16)(b * cs + a * sn);
    }
}

// ---------------------------------------------------------------- MFMA flash attention
// block = (kv_head, 16-row q tile); wave w handles q-head kvh*4+w.
// S^T = K·Q^T via MFMA (row=key, col=q): softmax reduce is in-lane + 2 shuffles.
// P round-trips LDS (C-layout -> A-layout). V staged transposed for b128 B-frags.
constexpr int KSP = 136;   // Ks row stride elems (272B, 16B-mult; 17r mod 32 distinct)
constexpr int VTP = 72;    // Vt row stride elems (144B, 16B-mult)
constexpr int PSP = 68;    // Ps row stride floats (272B)

__global__ __launch_bounds__(256) void flash_attn(const __bf16* __restrict__ qb,
                                                  const __bf16* __restrict__ kb,
                                                  const __bf16* __restrict__ vb,
                                                  __bf16* __restrict__ ob) {
    __shared__ __align__(16) __bf16 Ks[64 * KSP];
    __shared__ __align__(16) __bf16 Vt[128 * VTP];
    __shared__ __align__(16) float  Ps[4 * 16 * PSP];

    const int tid  = threadIdx.x;
    const int wave = tid >> 6, lane = tid & 63;
    const int bx   = blockIdx.x;
    const int kvh  = bx & 7;
    const int qt   = 127 - (bx >> 3);              // heavy tiles first
    const int h    = kvh * 4 + wave;
    const int r    = lane & 15, g = lane >> 4;
    const int qglob = qt * 16 + r;

    // Q fragments: lane holds Q[q=r][d = c*32 + g*8 + j]  (A/B frag layout)
    bf16x8 qfrag[4];
    const __bf16* qrow = qb + (size_t)(qt * 16 + r) * kH + h * kHD + g * 8;
#pragma unroll
    for (int c = 0; c < 4; c++) qfrag[c] = *(const bf16x8*)(qrow + c * 32);

    f32x4 o[8];
#pragma unroll
    for (int dt = 0; dt < 8; dt++) o[dt] = (f32x4)(0.f);
    float mrow = -3.0e38f, lrow = 0.f;
    float* Pw = Ps + wave * 16 * PSP;

    const int nkt = qt / 4 + 1;
    // staging addresses
    const int krow = tid & 63, kcb = (tid >> 6) * 32;   // K: row, elem base (64B/thread)
    for (int kt = 0; kt < nkt; ++kt) {
        // ---- stage K [64 keys][128 d]
        const __bf16* Kg = kb + (size_t)(kt * 64 + krow) * kKVD + kvh * kHD + kcb;
        __bf16* Kl = Ks + krow * KSP + kcb;
#pragma unroll
        for (int i = 0; i < 4; i++) *(bf16x8*)(Kl + i * 8) = *(const bf16x8*)(Kg + i * 8);
        // ---- stage V transposed: Vt[d][key], key-pairs packed to b32
#pragma unroll
        for (int i = 0; i < 2; i++) {
            int task = tid * 2 + i;                // 512 tasks: pair p (2 keys) x chunk c (8 d)
            int p = task & 31, c = task >> 5;
            const __bf16* v0 = vb + (size_t)(kt * 64 + 2 * p) * kKVD + kvh * kHD + c * 8;
            u16x8 a = __builtin_bit_cast(u16x8, *(const bf16x8*)v0);
            u16x8 b = __builtin_bit_cast(u16x8, *(const bf16x8*)(v0 + kKVD));
#pragma unroll
            for (int j = 0; j < 8; j++) {
                unsigned int pk = (unsigned int)a[j] | ((unsigned int)b[j] << 16);
                *(unsigned int*)(Vt + (c * 8 + j) * VTP + 2 * p) = pk;
            }
        }
        __syncthreads();

        // ---- S^T = K·Q^T : st[t] holds S^T[key = kt*64 + t*16 + g*4 + reg][q = r]
        f32x4 st[4];
#pragma unroll
        for (int t = 0; t < 4; t++) st[t] = (f32x4)(0.f);
#pragma unroll
        for (int c = 0; c < 4; c++) {
#pragma unroll
            for (int t = 0; t < 4; t++) {
                bf16x8 kf = *(const bf16x8*)&Ks[(t * 16 + r) * KSP + c * 32 + g * 8];
                st[t] = __builtin_amdgcn_mfma_f32_16x16x32_bf16(kf, qfrag[c], st[t], 0, 0, 0);
            }
        }

        // ---- causal mask + online softmax (per column q = r)
        float mloc = -3.0e38f;
#pragma unroll
        for (int t = 0; t < 4; t++)
#pragma unroll
            for (int reg = 0; reg < 4; reg++) {
                int key = kt * 64 + t * 16 + g * 4 + reg;
                float v = (key <= qglob) ? st[t][reg] : -3.0e38f;
                st[t][reg] = v;
                mloc = fmaxf(mloc, v);
            }
        mloc = fmaxf(mloc, __shfl_xor(mloc, 16));
        mloc = fmaxf(mloc, __shfl_xor(mloc, 32));
        float mnew  = fmaxf(mrow, mloc);
        float alpha = __expf(mrow - mnew);
        mrow = mnew;
        float lsum = 0.f;
#pragma unroll
        for (int t = 0; t < 4; t++)
#pragma unroll
            for (int reg = 0; reg < 4; reg++) {
                float pv = __expf(st[t][reg] - mnew);
                st[t][reg] = pv;
                lsum += pv;
            }
        lsum += __shfl_xor(lsum, 16);
        lsum += __shfl_xor(lsum, 32);
        lrow = lrow * alpha + lsum;

        // ---- rescale O by alpha of row q = g*4+reg
        float ar[4];
#pragma unroll
        for (int reg = 0; reg < 4; reg++) ar[reg] = __shfl(alpha, g * 4 + reg);
#pragma unroll
        for (int dt = 0; dt < 8; dt++)
#pragma unroll
            for (int reg = 0; reg < 4; reg++) o[dt][reg] *= ar[reg];

        // ---- P: C-layout -> LDS -> A-layout (wave-private, waitcnt only)
#pragma unroll
        for (int t = 0; t < 4; t++)
            *(f32x4*)&Pw[r * PSP + t * 16 + g * 4] = st[t];
        __asm__ volatile("s_waitcnt lgkmcnt(0)" ::: "memory");

#pragma unroll
        for (int kc = 0; kc < 2; kc++) {
            f32x4 p0 = *(const f32x4*)&Pw[r * PSP + kc * 32 + g * 8];
            f32x4 p1 = *(const f32x4*)&Pw[r * PSP + kc * 32 + g * 8 + 4];
            bf16x8 pf;
#pragma unroll
            for (int j = 0; j < 4; j++) { pf[j] = (__bf16)p0[j]; pf[j + 4] = (__bf16)p1[j]; }
#pragma unroll
            for (int dt = 0; dt < 8; dt++) {
                bf16x8 vf = *(const bf16x8*)&Vt[(dt * 16 + r) * VTP + kc * 32 + g * 8];
                o[dt] = __builtin_amdgcn_mfma_f32_16x16x32_bf16(pf, vf, o[dt], 0, 0, 0);
            }
        }
        __syncthreads();
    }

    // ---- epilogue: divide by l, store bf16
    float linv = 1.f / lrow;                       // for q = r, replicated over g
    float lr4[4];
#pragma unroll
    for (int reg = 0; reg < 4; reg++) lr4[reg] = __shfl(linv, g * 4 + reg);
#pragma unroll
    for (int dt = 0; dt < 8; dt++)
#pragma unroll
        for (int reg = 0; reg < 4; reg++) {
            int qq = g * 4 + reg, dd = dt * 16 + r;
            ob[(size_t)(qt * 16 + qq) * kH + h * kHD + dd] = (__bf16)(o[dt][reg] * lr4[reg]);
        }
}

// ---------------------------------------------------------------- launch
extern "C" void kernel_launch(void* const* d_in, const int* in_sizes, int n_in,
                              void* d_out, int out_size, void* d_ws, size_t ws_size,
                              hipStream_t stream) {
    const float* x  = (const float*)d_in[0];
    const float* wq = (const float*)d_in[1];
    const float* wk = (const float*)d_in[2];
    const float* wv = (const float*)d_in[3];
    const float* wo = (const float*)d_in[4];
    float* out = (float*)d_out;

    char* p = (char*)d_ws;
    auto alloc = [&](size_t bytes) {
        char* r = p;
        p += (bytes + 255) & ~(size_t)255;
        return r;
    };
    __bf16* xb  = (__bf16*)alloc((size_t)kS * kH * 2);      // x bf16; later attn out
    __bf16* wb1 = (__bf16*)alloc((size_t)kH * kH * 2);      // wq -> {qb,kb} -> wo
    __bf16* wb2 = (__bf16*)alloc((size_t)kKVD * kH * 2);    // wk -> wv -> vb
    float*  qf  = (float*)alloc((size_t)kS * kH * 4);
    float*  kf  = (float*)alloc((size_t)kS * kKVD * 4);
    float*  vf  = (float*)alloc((size_t)kS * kKVD * 4);
    __bf16* ao  = xb;
    __bf16* qbb = wb1;                                       // 16 MB
    __bf16* kbb = wb1 + (size_t)kS * kH;                     // 4 MB
    __bf16* vbb = wb2;                                       // 4 MB

    auto cvt = [&](const float* in, __bf16* o, size_t n) {
        int n4 = (int)(n / 4);
        cast_bf16<<<dim3((n4 + 255) / 256), dim3(256), 0, stream>>>(in, o, n4);
    };

    cvt(x, xb, (size_t)kS * kH);
    cvt(wq, wb1, (size_t)kH * kH);
    gemm_nt<<<dim3(kH / BN, kS / BM), 256, 0, stream>>>(xb, wb1, qf, kS, kH, kH);

    cvt(wk, wb2, (size_t)kKVD * kH);
    gemm_nt<<<dim3(kKVD / BN, kS / BM), 256, 0, stream>>>(xb, wb2, kf, kS, kKVD, kH);
    cvt(wv, wb2, (size_t)kKVD * kH);
    gemm_nt<<<dim3(kKVD / BN, kS / BM), 256, 0, stream>>>(xb, wb2, vf, kS, kKVD, kH);

    // RoPE + cast (wq in wb1 is dead now; qb/kb overlay it)
    rope_cast<<<dim3(kS * (kNH + kNKV) * 64 / 256), 256, 0, stream>>>(qf, kf, qbb, kbb);
    cvt(vf, vbb, (size_t)kS * kKVD);                         // wk/wv dead

    flash_attn<<<dim3(kNKV * (kS / 16)), 256, 0, stream>>>(qbb, kbb, vbb, ao);

    cvt(wo, wb1, (size_t)kH * kH);                           // qb/kb dead
    gemm_nt<<<dim3(kH / BN, kS / BM), 256, 0, stream>>>(ao, wb1, out, kS, kH, kH);
}

// Round 3
// 564.577 us; speedup vs baseline: 9.4357x; 1.3220x over previous
//
#include <hip/hip_runtime.h>
#include <hip/hip_bf16.h>
#include <math.h>

typedef __bf16 bf16x8 __attribute__((ext_vector_type(8)));
typedef __bf16 bf16x4 __attribute__((ext_vector_type(4)));
typedef unsigned short u16x8 __attribute__((ext_vector_type(8)));
typedef float  f32x4  __attribute__((ext_vector_type(4)));

constexpr int kS   = 2048;
constexpr int kH   = 4096;
constexpr int kNH  = 32;
constexpr int kNKV = 8;
constexpr int kHD  = 128;
constexpr int kQKV = kH + 2 * kNKV * kHD;   // 6144: [Q 4096 | K 1024 | V 1024]
constexpr int kKOff = kH;                    // 4096
constexpr int kVOff = kH + kNKV * kHD;       // 5120

// ---------------------------------------------------------------- generic cast
__global__ void cast_bf16(const float* __restrict__ in, __bf16* __restrict__ out, int n4) {
    int i = blockIdx.x * blockDim.x + threadIdx.x;
    if (i < n4) {
        float4 f = ((const float4*)in)[i];
        bf16x4 o;
        o[0] = (__bf16)f.x; o[1] = (__bf16)f.y; o[2] = (__bf16)f.z; o[3] = (__bf16)f.w;
        ((bf16x4*)out)[i] = o;
    }
}

// ---------------------------------------------------------------- fused cast: x -> xb, wq|wk|wv -> wqkv (rows stacked)
// float4 sizes: x 2M, wq 4M, wk 1M, wv 1M (total 8M threads)
__global__ void cast_all(const float* __restrict__ x, const float* __restrict__ wq,
                         const float* __restrict__ wk, const float* __restrict__ wv,
                         __bf16* __restrict__ xb, __bf16* __restrict__ wqkv) {
    int i = blockIdx.x * 256 + threadIdx.x;
    float4 f;
    __bf16* dst;
    int di;
    if (i < (1 << 21)) {
        f = ((const float4*)x)[i];
        dst = xb; di = i;
    } else {
        int j = i - (1 << 21);
        const float4* s = (j < (1 << 22)) ? ((const float4*)wq + j)
                        : (j < (5 << 20)) ? ((const float4*)wk + (j - (1 << 22)))
                                          : ((const float4*)wv + (j - (5 << 20)));
        f = *s;
        dst = wqkv; di = j;
    }
    bf16x4 o;
    o[0] = (__bf16)f.x; o[1] = (__bf16)f.y; o[2] = (__bf16)f.z; o[3] = (__bf16)f.w;
    ((bf16x4*)dst)[di] = o;
}

// ---------------------------------------------------------------- m97-style NT GEMM
// C[M,N] = A[M,K]*B[N,K]^T, bf16 in, OutT out. global_load_lds width-16 staging,
// unpadded LDS (dest must be wave-uniform base + lane*16 -- no padding possible).
constexpr int BM = 128, BN = 128, BK = 32;

__device__ inline void gld16(const __bf16* g, __bf16* l) {
    __builtin_amdgcn_global_load_lds((const __attribute__((address_space(1))) void*)g,
                                     (__attribute__((address_space(3))) void*)l, 16, 0, 0);
}

template <typename OutT>
__global__ __launch_bounds__(256) void gemm_nt(const __bf16* __restrict__ A,
                                               const __bf16* __restrict__ B,
                                               OutT* __restrict__ C,
                                               int M, int N, int K) {
    __shared__ __align__(16) __bf16 As[BM * BK];   // 8 KB, linear [row][32]
    __shared__ __align__(16) __bf16 Bs[BN * BK];
    const int tid  = threadIdx.x;
    const int w    = tid >> 6, lane = tid & 63;
    const int m0   = blockIdx.y * BM, n0 = blockIdx.x * BN;
    const int wm   = (w >> 1) * 64, wn = (w & 1) * 64;
    const int lr   = lane & 15, lk = (lane >> 4) * 8;

    // staging: 512 16B-chunks per tile; wave w, call c covers chunks (w*2+c)*64 + lane
    const int ci0 = w * 128 + lane;
    const int ci1 = ci0 + 64;
    const __bf16* gA0 = A + (size_t)(m0 + (ci0 >> 2)) * K + (ci0 & 3) * 8;
    const __bf16* gA1 = A + (size_t)(m0 + (ci1 >> 2)) * K + (ci1 & 3) * 8;
    const __bf16* gB0 = B + (size_t)(n0 + (ci0 >> 2)) * K + (ci0 & 3) * 8;
    const __bf16* gB1 = B + (size_t)(n0 + (ci1 >> 2)) * K + (ci1 & 3) * 8;
    __bf16* lA0 = As + w * 1024;        // wave-uniform LDS bases (elems)
    __bf16* lA1 = As + w * 1024 + 512;
    __bf16* lB0 = Bs + w * 1024;
    __bf16* lB1 = Bs + w * 1024 + 512;

    f32x4 acc[4][4];
#pragma unroll
    for (int i = 0; i < 4; i++)
#pragma unroll
        for (int j = 0; j < 4; j++) acc[i][j] = (f32x4)(0.f);

    for (int k0 = 0; k0 < K; k0 += BK) {
        gld16(gA0 + k0, lA0);
        gld16(gA1 + k0, lA1);
        gld16(gB0 + k0, lB0);
        gld16(gB1 + k0, lB1);
        __syncthreads();

        bf16x8 af[4], bfr[4];
#pragma unroll
        for (int i = 0; i < 4; i++) af[i]  = *(const bf16x8*)&As[(wm + i * 16 + lr) * BK + lk];
#pragma unroll
        for (int j = 0; j < 4; j++) bfr[j] = *(const bf16x8*)&Bs[(wn + j * 16 + lr) * BK + lk];

#pragma unroll
        for (int i = 0; i < 4; i++)
#pragma unroll
            for (int j = 0; j < 4; j++)
                acc[i][j] = __builtin_amdgcn_mfma_f32_16x16x32_bf16(af[i], bfr[j], acc[i][j], 0, 0, 0);
        __syncthreads();
    }

    // C/D layout: col = lane&15, row = (lane>>4)*4 + reg
    const int cr = (lane >> 4) * 4, cc = lane & 15;
#pragma unroll
    for (int i = 0; i < 4; i++)
#pragma unroll
        for (int j = 0; j < 4; j++) {
            OutT* Cp = C + (size_t)(m0 + wm + i * 16 + cr) * N + (n0 + wn + j * 16 + cc);
#pragma unroll
            for (int r = 0; r < 4; r++) Cp[(size_t)r * N] = (OutT)acc[i][j][r];
        }
}

// ---------------------------------------------------------------- RoPE in-place on qkv bf16 [S, 6144]
// Q heads scaled by 1/sqrt(128); V untouched.
__global__ void rope_qkv(__bf16* __restrict__ qkv) {
    int idx  = blockIdx.x * 256 + threadIdx.x;   // S * 40 * 64
    int d    = idx & 63;
    int rest = idx >> 6;
    int hh   = rest % (kNH + kNKV);
    int s    = rest / (kNH + kNKV);
    float inv_freq = powf(500000.0f, -(float)d * (1.0f / 64.0f));
    float sn, cs;
    sincosf((float)s * inv_freq, &sn, &cs);
    __bf16* base = qkv + (size_t)s * kQKV + ((hh < kNH) ? hh * kHD : kKOff + (hh - kNH) * kHD);
    float sc = (hh < kNH) ? 0.088388347648318447f : 1.0f;
    float a = (float)base[d], b = (float)base[d + 64];
    base[d]      = (__bf16)((a * cs - b * sn) * sc);
    base[d + 64] = (__bf16)((b * cs + a * sn) * sc);
}

// ---------------------------------------------------------------- MFMA flash attention (GQA)
// block = (kv_head, 16-row q tile); wave w = q-head kvh*4+w. Q/K/V read from qkv [S,6144].
constexpr int KSP = 136;
constexpr int VTP = 72;
constexpr int PSP = 68;

__global__ __launch_bounds__(256) void flash_attn(const __bf16* __restrict__ qkv,
                                                  __bf16* __restrict__ ob) {
    __shared__ __align__(16) __bf16 Ks[64 * KSP];
    __shared__ __align__(16) __bf16 Vt[128 * VTP];
    __shared__ __align__(16) float  Ps[4 * 16 * PSP];

    const int tid  = threadIdx.x;
    const int wave = tid >> 6, lane = tid & 63;
    const int bx   = blockIdx.x;
    const int kvh  = bx & 7;
    const int qt   = 127 - (bx >> 3);              // heavy tiles first
    const int h    = kvh * 4 + wave;
    const int r    = lane & 15, g = lane >> 4;
    const int qglob = qt * 16 + r;

    bf16x8 qfrag[4];
    const __bf16* qrow = qkv + (size_t)(qt * 16 + r) * kQKV + h * kHD + g * 8;
#pragma unroll
    for (int c = 0; c < 4; c++) qfrag[c] = *(const bf16x8*)(qrow + c * 32);

    f32x4 o[8];
#pragma unroll
    for (int dt = 0; dt < 8; dt++) o[dt] = (f32x4)(0.f);
    float mrow = -3.0e38f, lrow = 0.f;
    float* Pw = Ps + wave * 16 * PSP;

    const int nkt = qt / 4 + 1;
    const int krow = tid & 63, kcb = (tid >> 6) * 32;
    const __bf16* kbase = qkv + kKOff + kvh * kHD;
    const __bf16* vbase = qkv + kVOff + kvh * kHD;

    for (int kt = 0; kt < nkt; ++kt) {
        // ---- stage K [64 keys][128 d]
        const __bf16* Kg = kbase + (size_t)(kt * 64 + krow) * kQKV + kcb;
        __bf16* Kl = Ks + krow * KSP + kcb;
#pragma unroll
        for (int i = 0; i < 4; i++) *(bf16x8*)(Kl + i * 8) = *(const bf16x8*)(Kg + i * 8);
        // ---- stage V transposed: Vt[d][key]
#pragma unroll
        for (int i = 0; i < 2; i++) {
            int task = tid * 2 + i;
            int p = task & 31, c = task >> 5;
            const __bf16* v0 = vbase + (size_t)(kt * 64 + 2 * p) * kQKV + c * 8;
            u16x8 a = __builtin_bit_cast(u16x8, *(const bf16x8*)v0);
            u16x8 b = __builtin_bit_cast(u16x8, *(const bf16x8*)(v0 + kQKV));
#pragma unroll
            for (int j = 0; j < 8; j++) {
                unsigned int pk = (unsigned int)a[j] | ((unsigned int)b[j] << 16);
                *(unsigned int*)(Vt + (c * 8 + j) * VTP + 2 * p) = pk;
            }
        }
        __syncthreads();

        // ---- S^T = K·Q^T
        f32x4 st[4];
#pragma unroll
        for (int t = 0; t < 4; t++) st[t] = (f32x4)(0.f);
#pragma unroll
        for (int c = 0; c < 4; c++) {
#pragma unroll
            for (int t = 0; t < 4; t++) {
                bf16x8 kf = *(const bf16x8*)&Ks[(t * 16 + r) * KSP + c * 32 + g * 8];
                st[t] = __builtin_amdgcn_mfma_f32_16x16x32_bf16(kf, qfrag[c], st[t], 0, 0, 0);
            }
        }

        // ---- causal mask + online softmax (per q = r)
        float mloc = -3.0e38f;
#pragma unroll
        for (int t = 0; t < 4; t++)
#pragma unroll
            for (int reg = 0; reg < 4; reg++) {
                int key = kt * 64 + t * 16 + g * 4 + reg;
                float v = (key <= qglob) ? st[t][reg] : -3.0e38f;
                st[t][reg] = v;
                mloc = fmaxf(mloc, v);
            }
        mloc = fmaxf(mloc, __shfl_xor(mloc, 16));
        mloc = fmaxf(mloc, __shfl_xor(mloc, 32));
        float mnew  = fmaxf(mrow, mloc);
        float alpha = __expf(mrow - mnew);
        mrow = mnew;
        float lsum = 0.f;
#pragma unroll
        for (int t = 0; t < 4; t++)
#pragma unroll
            for (int reg = 0; reg < 4; reg++) {
                float pv = __expf(st[t][reg] - mnew);
                st[t][reg] = pv;
                lsum += pv;
            }
        lsum += __shfl_xor(lsum, 16);
        lsum += __shfl_xor(lsum, 32);
        lrow = lrow * alpha + lsum;

        float ar[4];
#pragma unroll
        for (int reg = 0; reg < 4; reg++) ar[reg] = __shfl(alpha, g * 4 + reg);
#pragma unroll
        for (int dt = 0; dt < 8; dt++)
#pragma unroll
            for (int reg = 0; reg < 4; reg++) o[dt][reg] *= ar[reg];

        // ---- P: C-layout -> LDS -> A-layout (wave-private)
#pragma unroll
        for (int t = 0; t < 4; t++)
            *(f32x4*)&Pw[r * PSP + t * 16 + g * 4] = st[t];
        __asm__ volatile("s_waitcnt lgkmcnt(0)" ::: "memory");

#pragma unroll
        for (int kc = 0; kc < 2; kc++) {
            f32x4 p0 = *(const f32x4*)&Pw[r * PSP + kc * 32 + g * 8];
            f32x4 p1 = *(const f32x4*)&Pw[r * PSP + kc * 32 + g * 8 + 4];
            bf16x8 pf;
#pragma unroll
            for (int j = 0; j < 4; j++) { pf[j] = (__bf16)p0[j]; pf[j + 4] = (__bf16)p1[j]; }
#pragma unroll
            for (int dt = 0; dt < 8; dt++) {
                bf16x8 vf = *(const bf16x8*)&Vt[(dt * 16 + r) * VTP + kc * 32 + g * 8];
                o[dt] = __builtin_amdgcn_mfma_f32_16x16x32_bf16(pf, vf, o[dt], 0, 0, 0);
            }
        }
        __syncthreads();
    }

    float linv = 1.f / lrow;
    float lr4[4];
#pragma unroll
    for (int reg = 0; reg < 4; reg++) lr4[reg] = __shfl(linv, g * 4 + reg);
#pragma unroll
    for (int dt = 0; dt < 8; dt++)
#pragma unroll
        for (int reg = 0; reg < 4; reg++) {
            int qq = g * 4 + reg, dd = dt * 16 + r;
            ob[(size_t)(qt * 16 + qq) * kH + h * kHD + dd] = (__bf16)(o[dt][reg] * lr4[reg]);
        }
}

// ---------------------------------------------------------------- launch
extern "C" void kernel_launch(void* const* d_in, const int* in_sizes, int n_in,
                              void* d_out, int out_size, void* d_ws, size_t ws_size,
                              hipStream_t stream) {
    const float* x  = (const float*)d_in[0];
    const float* wq = (const float*)d_in[1];
    const float* wk = (const float*)d_in[2];
    const float* wv = (const float*)d_in[3];
    const float* wo = (const float*)d_in[4];
    float* out = (float*)d_out;

    char* p = (char*)d_ws;
    auto alloc = [&](size_t bytes) {
        char* r = p;
        p += (bytes + 255) & ~(size_t)255;
        return r;
    };
    __bf16* xb    = (__bf16*)alloc((size_t)kS * kH * 2);        // 16 MB; later attn out
    __bf16* wqkvb = (__bf16*)alloc((size_t)kQKV * kH * 2);      // 48 MB; later wo bf16
    __bf16* qkv   = (__bf16*)alloc((size_t)kS * kQKV * 2);      // 24 MB
    __bf16* ao    = xb;                                          // overlay (xb dead after gemm_qkv)
    __bf16* wob   = wqkvb;                                       // overlay (wqkvb dead after gemm_qkv)

    cast_all<<<dim3(1 << 15), 256, 0, stream>>>(x, wq, wk, wv, xb, wqkvb);

    gemm_nt<__bf16><<<dim3(kQKV / BN, kS / BM), 256, 0, stream>>>(xb, wqkvb, qkv, kS, kQKV, kH);

    rope_qkv<<<dim3(kS * (kNH + kNKV) * 64 / 256), 256, 0, stream>>>(qkv);

    cast_bf16<<<dim3((kH * kH / 4) / 256), 256, 0, stream>>>(wo, wob, kH * kH / 4);

    flash_attn<<<dim3(kNKV * (kS / 16)), 256, 0, stream>>>(qkv, ao);

    gemm_nt<float><<<dim3(kH / BN, kS / BM), 256, 0, stream>>>(ao, wob, out, kS, kH, kH);
}

// Round 4
// 529.013 us; speedup vs baseline: 10.0700x; 1.0672x over previous
//
#include <hip/hip_runtime.h>
#include <hip/hip_bf16.h>
#include <math.h>

typedef __bf16 bf16x8 __attribute__((ext_vector_type(8)));
typedef __bf16 bf16x4 __attribute__((ext_vector_type(4)));
typedef unsigned short u16x8 __attribute__((ext_vector_type(8)));
typedef float  f32x4  __attribute__((ext_vector_type(4)));

constexpr int kS   = 2048;
constexpr int kH   = 4096;
constexpr int kNH  = 32;
constexpr int kNKV = 8;
constexpr int kHD  = 128;
constexpr int kQKV = kH + 2 * kNKV * kHD;   // 6144: [Q 4096 | K 1024 | V 1024]
constexpr int kKOff = kH;                    // 4096
constexpr int kVOff = kH + kNKV * kHD;       // 5120

// ---------------------------------------------------------------- generic cast
__global__ void cast_bf16(const float* __restrict__ in, __bf16* __restrict__ out, int n4) {
    int i = blockIdx.x * blockDim.x + threadIdx.x;
    if (i < n4) {
        float4 f = ((const float4*)in)[i];
        bf16x4 o;
        o[0] = (__bf16)f.x; o[1] = (__bf16)f.y; o[2] = (__bf16)f.z; o[3] = (__bf16)f.w;
        ((bf16x4*)out)[i] = o;
    }
}

// ---------------------------------------------------------------- fused cast: x -> xb, wq|wk|wv -> wqkv
__global__ void cast_all(const float* __restrict__ x, const float* __restrict__ wq,
                         const float* __restrict__ wk, const float* __restrict__ wv,
                         __bf16* __restrict__ xb, __bf16* __restrict__ wqkv) {
    int i = blockIdx.x * 256 + threadIdx.x;
    float4 f;
    __bf16* dst;
    int di;
    if (i < (1 << 21)) {
        f = ((const float4*)x)[i];
        dst = xb; di = i;
    } else {
        int j = i - (1 << 21);
        const float4* s = (j < (1 << 22)) ? ((const float4*)wq + j)
                        : (j < (5 << 20)) ? ((const float4*)wk + (j - (1 << 22)))
                                          : ((const float4*)wv + (j - (5 << 20)));
        f = *s;
        dst = wqkv; di = j;
    }
    bf16x4 o;
    o[0] = (__bf16)f.x; o[1] = (__bf16)f.y; o[2] = (__bf16)f.z; o[3] = (__bf16)f.w;
    ((bf16x4*)dst)[di] = o;
}

// ---------------------------------------------------------------- m97-style NT GEMM, BK=64, XOR-swizzled LDS
// C[M,N] = A[M,K]*B[N,K]^T, bf16 in, OutT out. global_load_lds width-16.
// LDS layout: row r's 16B-chunk c stored at slot (c ^ (r&7)) -> bank-uniform
// b128 reads at 128B row stride. Staging lanes fetch the swizzled global chunk
// so the HW's forced dest (base + lane*16) lands each chunk in its slot.
constexpr int BM = 128, BN = 128, BK = 64;

__device__ inline void gld16(const __bf16* g, __bf16* l) {
    __builtin_amdgcn_global_load_lds((const __attribute__((address_space(1))) void*)g,
                                     (__attribute__((address_space(3))) void*)l, 16, 0, 0);
}

template <typename OutT>
__global__ __launch_bounds__(256) void gemm_nt(const __bf16* __restrict__ A,
                                               const __bf16* __restrict__ B,
                                               OutT* __restrict__ C,
                                               int M, int N, int K) {
    __shared__ __align__(16) __bf16 As[BM * BK];   // 16 KB
    __shared__ __align__(16) __bf16 Bs[BN * BK];   // 16 KB
    const int tid  = threadIdx.x;
    const int w    = tid >> 6, lane = tid & 63;
    const int m0   = blockIdx.y * BM, n0 = blockIdx.x * BN;
    const int wm   = (w >> 1) * 64, wn = (w & 1) * 64;
    const int lr   = lane & 15, g8 = lane >> 4;

    // staging: tile = 128 rows x 8 chunks = 1024 chunks; 16 groups of 64 (8 rows).
    // wave w stages groups w*4 .. w*4+3. lane l -> row l>>3, global chunk (l&7)^(l>>3).
    const int l3 = lane >> 3;
    const int lc = (lane & 7) ^ l3;
    const __bf16 *gA[4], *gB[4];
    __bf16 *lA[4], *lB[4];
#pragma unroll
    for (int c = 0; c < 4; c++) {
        int G = w * 4 + c;
        gA[c] = A + (size_t)(m0 + G * 8 + l3) * K + lc * 8;
        gB[c] = B + (size_t)(n0 + G * 8 + l3) * K + lc * 8;
        lA[c] = As + G * 512;
        lB[c] = Bs + G * 512;
    }

    f32x4 acc[4][4];
#pragma unroll
    for (int i = 0; i < 4; i++)
#pragma unroll
        for (int j = 0; j < 4; j++) acc[i][j] = (f32x4)(0.f);

    for (int k0 = 0; k0 < K; k0 += BK) {
#pragma unroll
        for (int c = 0; c < 4; c++) {
            gld16(gA[c] + k0, lA[c]);
            gld16(gB[c] + k0, lB[c]);
        }
        __syncthreads();

        const int rx = lr & 7;
#pragma unroll
        for (int kc = 0; kc < 2; kc++) {
            bf16x8 af[4], bfr[4];
#pragma unroll
            for (int i = 0; i < 4; i++)
                af[i]  = *(const bf16x8*)&As[(wm + i * 16 + lr) * BK + (((kc * 4 + g8) ^ rx) * 8)];
#pragma unroll
            for (int j = 0; j < 4; j++)
                bfr[j] = *(const bf16x8*)&Bs[(wn + j * 16 + lr) * BK + (((kc * 4 + g8) ^ rx) * 8)];
#pragma unroll
            for (int i = 0; i < 4; i++)
#pragma unroll
                for (int j = 0; j < 4; j++)
                    acc[i][j] = __builtin_amdgcn_mfma_f32_16x16x32_bf16(af[i], bfr[j], acc[i][j], 0, 0, 0);
        }
        __syncthreads();
    }

    // C/D layout: col = lane&15, row = (lane>>4)*4 + reg
    const int cr = g8 * 4, cc = lr;
#pragma unroll
    for (int i = 0; i < 4; i++)
#pragma unroll
        for (int j = 0; j < 4; j++) {
            OutT* Cp = C + (size_t)(m0 + wm + i * 16 + cr) * N + (n0 + wn + j * 16 + cc);
#pragma unroll
            for (int r = 0; r < 4; r++) Cp[(size_t)r * N] = (OutT)acc[i][j][r];
        }
}

// ---------------------------------------------------------------- RoPE in-place on qkv bf16 [S, 6144]
__global__ void rope_qkv(__bf16* __restrict__ qkv) {
    int idx  = blockIdx.x * 256 + threadIdx.x;   // S * 40 * 64
    int d    = idx & 63;
    int rest = idx >> 6;
    int hh   = rest % (kNH + kNKV);
    int s    = rest / (kNH + kNKV);
    float inv_freq = powf(500000.0f, -(float)d * (1.0f / 64.0f));
    float sn, cs;
    sincosf((float)s * inv_freq, &sn, &cs);
    __bf16* base = qkv + (size_t)s * kQKV + ((hh < kNH) ? hh * kHD : kKOff + (hh - kNH) * kHD);
    float sc = (hh < kNH) ? 0.088388347648318447f : 1.0f;
    float a = (float)base[d], b = (float)base[d + 64];
    base[d]      = (__bf16)((a * cs - b * sn) * sc);
    base[d + 64] = (__bf16)((b * cs + a * sn) * sc);
}

// ---------------------------------------------------------------- MFMA flash attention (GQA)
constexpr int KSP = 136;
constexpr int VTP = 72;
constexpr int PSP = 68;

__global__ __launch_bounds__(256) void flash_attn(const __bf16* __restrict__ qkv,
                                                  __bf16* __restrict__ ob) {
    __shared__ __align__(16) __bf16 Ks[64 * KSP];
    __shared__ __align__(16) __bf16 Vt[128 * VTP];
    __shared__ __align__(16) float  Ps[4 * 16 * PSP];

    const int tid  = threadIdx.x;
    const int wave = tid >> 6, lane = tid & 63;
    const int bx   = blockIdx.x;
    const int kvh  = bx & 7;
    const int qt   = 127 - (bx >> 3);              // heavy tiles first
    const int h    = kvh * 4 + wave;
    const int r    = lane & 15, g = lane >> 4;
    const int qglob = qt * 16 + r;

    bf16x8 qfrag[4];
    const __bf16* qrow = qkv + (size_t)(qt * 16 + r) * kQKV + h * kHD + g * 8;
#pragma unroll
    for (int c = 0; c < 4; c++) qfrag[c] = *(const bf16x8*)(qrow + c * 32);

    f32x4 o[8];
#pragma unroll
    for (int dt = 0; dt < 8; dt++) o[dt] = (f32x4)(0.f);
    float mrow = -3.0e38f, lrow = 0.f;
    float* Pw = Ps + wave * 16 * PSP;

    const int nkt = qt / 4 + 1;
    const int krow = tid & 63, kcb = (tid >> 6) * 32;
    const __bf16* kbase = qkv + kKOff + kvh * kHD;
    const __bf16* vbase = qkv + kVOff + kvh * kHD;

    for (int kt = 0; kt < nkt; ++kt) {
        // ---- stage K [64 keys][128 d]
        const __bf16* Kg = kbase + (size_t)(kt * 64 + krow) * kQKV + kcb;
        __bf16* Kl = Ks + krow * KSP + kcb;
#pragma unroll
        for (int i = 0; i < 4; i++) *(bf16x8*)(Kl + i * 8) = *(const bf16x8*)(Kg + i * 8);
        // ---- stage V transposed: Vt[d][key]
#pragma unroll
        for (int i = 0; i < 2; i++) {
            int task = tid * 2 + i;
            int p = task & 31, c = task >> 5;
            const __bf16* v0 = vbase + (size_t)(kt * 64 + 2 * p) * kQKV + c * 8;
            u16x8 a = __builtin_bit_cast(u16x8, *(const bf16x8*)v0);
            u16x8 b = __builtin_bit_cast(u16x8, *(const bf16x8*)(v0 + kQKV));
#pragma unroll
            for (int j = 0; j < 8; j++) {
                unsigned int pk = (unsigned int)a[j] | ((unsigned int)b[j] << 16);
                *(unsigned int*)(Vt + (c * 8 + j) * VTP + 2 * p) = pk;
            }
        }
        __syncthreads();

        // ---- S^T = K·Q^T
        f32x4 st[4];
#pragma unroll
        for (int t = 0; t < 4; t++) st[t] = (f32x4)(0.f);
#pragma unroll
        for (int c = 0; c < 4; c++) {
#pragma unroll
            for (int t = 0; t < 4; t++) {
                bf16x8 kf = *(const bf16x8*)&Ks[(t * 16 + r) * KSP + c * 32 + g * 8];
                st[t] = __builtin_amdgcn_mfma_f32_16x16x32_bf16(kf, qfrag[c], st[t], 0, 0, 0);
            }
        }

        // ---- causal mask + online softmax (per q = r)
        float mloc = -3.0e38f;
#pragma unroll
        for (int t = 0; t < 4; t++)
#pragma unroll
            for (int reg = 0; reg < 4; reg++) {
                int key = kt * 64 + t * 16 + g * 4 + reg;
                float v = (key <= qglob) ? st[t][reg] : -3.0e38f;
                st[t][reg] = v;
                mloc = fmaxf(mloc, v);
            }
        mloc = fmaxf(mloc, __shfl_xor(mloc, 16));
        mloc = fmaxf(mloc, __shfl_xor(mloc, 32));
        float mnew  = fmaxf(mrow, mloc);
        float alpha = __expf(mrow - mnew);
        mrow = mnew;
        float lsum = 0.f;
#pragma unroll
        for (int t = 0; t < 4; t++)
#pragma unroll
            for (int reg = 0; reg < 4; reg++) {
                float pv = __expf(st[t][reg] - mnew);
                st[t][reg] = pv;
                lsum += pv;
            }
        lsum += __shfl_xor(lsum, 16);
        lsum += __shfl_xor(lsum, 32);
        lrow = lrow * alpha + lsum;

        float ar[4];
#pragma unroll
        for (int reg = 0; reg < 4; reg++) ar[reg] = __shfl(alpha, g * 4 + reg);
#pragma unroll
        for (int dt = 0; dt < 8; dt++)
#pragma unroll
            for (int reg = 0; reg < 4; reg++) o[dt][reg] *= ar[reg];

        // ---- P: C-layout -> LDS -> A-layout (wave-private)
#pragma unroll
        for (int t = 0; t < 4; t++)
            *(f32x4*)&Pw[r * PSP + t * 16 + g * 4] = st[t];
        __asm__ volatile("s_waitcnt lgkmcnt(0)" ::: "memory");

#pragma unroll
        for (int kc = 0; kc < 2; kc++) {
            f32x4 p0 = *(const f32x4*)&Pw[r * PSP + kc * 32 + g * 8];
            f32x4 p1 = *(const f32x4*)&Pw[r * PSP + kc * 32 + g * 8 + 4];
            bf16x8 pf;
#pragma unroll
            for (int j = 0; j < 4; j++) { pf[j] = (__bf16)p0[j]; pf[j + 4] = (__bf16)p1[j]; }
#pragma unroll
            for (int dt = 0; dt < 8; dt++) {
                bf16x8 vf = *(const bf16x8*)&Vt[(dt * 16 + r) * VTP + kc * 32 + g * 8];
                o[dt] = __builtin_amdgcn_mfma_f32_16x16x32_bf16(pf, vf, o[dt], 0, 0, 0);
            }
        }
        __syncthreads();
    }

    float linv = 1.f / lrow;
    float lr4[4];
#pragma unroll
    for (int reg = 0; reg < 4; reg++) lr4[reg] = __shfl(linv, g * 4 + reg);
#pragma unroll
    for (int dt = 0; dt < 8; dt++)
#pragma unroll
        for (int reg = 0; reg < 4; reg++) {
            int qq = g * 4 + reg, dd = dt * 16 + r;
            ob[(size_t)(qt * 16 + qq) * kH + h * kHD + dd] = (__bf16)(o[dt][reg] * lr4[reg]);
        }
}

// ---------------------------------------------------------------- launch
extern "C" void kernel_launch(void* const* d_in, const int* in_sizes, int n_in,
                              void* d_out, int out_size, void* d_ws, size_t ws_size,
                              hipStream_t stream) {
    const float* x  = (const float*)d_in[0];
    const float* wq = (const float*)d_in[1];
    const float* wk = (const float*)d_in[2];
    const float* wv = (const float*)d_in[3];
    const float* wo = (const float*)d_in[4];
    float* out = (float*)d_out;

    char* p = (char*)d_ws;
    auto alloc = [&](size_t bytes) {
        char* r = p;
        p += (bytes + 255) & ~(size_t)255;
        return r;
    };
    __bf16* xb    = (__bf16*)alloc((size_t)kS * kH * 2);        // 16 MB; later attn out
    __bf16* wqkvb = (__bf16*)alloc((size_t)kQKV * kH * 2);      // 48 MB; later wo bf16
    __bf16* qkv   = (__bf16*)alloc((size_t)kS * kQKV * 2);      // 24 MB
    __bf16* ao    = xb;                                          // overlay (xb dead after gemm_qkv)
    __bf16* wob   = wqkvb;                                       // overlay (wqkvb dead after gemm_qkv)

    cast_all<<<dim3(1 << 15), 256, 0, stream>>>(x, wq, wk, wv, xb, wqkvb);

    gemm_nt<__bf16><<<dim3(kQKV / BN, kS / BM), 256, 0, stream>>>(xb, wqkvb, qkv, kS, kQKV, kH);

    rope_qkv<<<dim3(kS * (kNH + kNKV) * 64 / 256), 256, 0, stream>>>(qkv);

    cast_bf16<<<dim3((kH * kH / 4) / 256), 256, 0, stream>>>(wo, wob, kH * kH / 4);

    flash_attn<<<dim3(kNKV * (kS / 16)), 256, 0, stream>>>(qkv, ao);

    gemm_nt<float><<<dim3(kH / BN, kS / BM), 256, 0, stream>>>(ao, wob, out, kS, kH, kH);
}